// Round 4
// baseline (554.438 us; speedup 1.0000x reference)
//
#include <hip/hip_runtime.h>
#include <stdint.h>

#define EPS 1e-20f
#define H_ 192
#define W_ 192
#define HW_ 36864
#define CH4 128
#define OUTELEMS 18874368  // 4*128*36864 elements per output tensor

// ---- bf16 pack helpers (RNE) for intermediates ----
__device__ __forceinline__ unsigned short f2bf(float f) {
  unsigned u = __float_as_uint(f);
  return (unsigned short)((u + 0x7fffu + ((u >> 16) & 1u)) >> 16);
}
__device__ __forceinline__ float bflo(unsigned v) { return __uint_as_float(v << 16); }
__device__ __forceinline__ float bfhi(unsigned v) { return __uint_as_float(v & 0xffff0000u); }

// ---- k0: transpose channel_weight (f32) + global sums ----
__global__ void __launch_bounds__(256) k0_prep(const float* __restrict__ cw,
                                               const float* __restrict__ sw,
                                               float* __restrict__ cwT,
                                               float* __restrict__ sums) {
  int tid = threadIdx.x;
  if (blockIdx.x < 64) {
    int idx = blockIdx.x * 256 + tid;
    int o = idx >> 7, i = idx & 127;
    cwT[i * 128 + o] = cw[idx];
  } else {
    __shared__ float red[256];
    float s = 0.f;
    for (int k = tid; k < 16384; k += 256) s += cw[k];
    red[tid] = s; __syncthreads();
    for (int off = 128; off > 0; off >>= 1) {
      if (tid < off) red[tid] += red[tid + off];
      __syncthreads();
    }
    if (tid == 0) sums[0] = red[0];
    __syncthreads();
    s = 0.f;
    for (int k = tid; k < 3200; k += 256) s += sw[k];
    red[tid] = s; __syncthreads();
    for (int off = 128; off > 0; off >>= 1) {
      if (tid < off) red[tid] += red[tid + off];
      __syncthreads();
    }
    if (tid == 0) sums[1] = red[0];
  }
}

// ---- k1: stencil stage -> packed (X=ce1*e1, Y=ce1) bf16x2, planar (B,128,H,W) ----
__global__ void __launch_bounds__(256) k1_stage1(
    const float* __restrict__ d, const float* __restrict__ cd,
    const float* __restrict__ e, const float* __restrict__ ce,
    const float* __restrict__ wprop, const float* __restrict__ wsd,
    unsigned* __restrict__ XY) {
  const int tid = threadIdx.x;
  const int tile = blockIdx.x;  // 36 tiles of 32x32
  const int th0 = (tile / 6) * 32, tw0 = (tile % 6) * 32;
  const int bc = blockIdx.y;  // b*32+c
  const int b = bc >> 5, c = bc & 31;

  // dpL covers original rows th0-2..th0+33 (padded coords th0-1..th0+34)
  __shared__ float dpL[1296], cdpL[1296];
  // min/max maps at padded positions [th0, th0+34)
  __shared__ float dmnL[1156], dmxL[1156], cmnL[1156], cmxL[1156];

  const float* dB = d + bc * HW_;
  const float* cdB = cd + bc * HW_;
  for (int idx = tid; idx < 1296; idx += 256) {
    int ly = idx / 36, lx = idx % 36;
    int gy = th0 + ly - 2, gx = tw0 + lx - 2;  // original-image coords
    float dv = 0.f, cv = 0.f;
    if (gy >= 0 && gy < H_ && gx >= 0 && gx < W_) {
      dv = dB[gy * W_ + gx];
      cv = cdB[gy * W_ + gx];
    }
    dpL[idx] = dv; cdpL[idx] = cv;
  }
  __syncthreads();

  for (int idx = tid; idx < 1156; idx += 256) {
    int ly = idx / 34, lx = idx % 34;
    float bkx = -1.f, bkn = -1.f;  // keys are >=0; -1 acts as -inf sentinel
    float dmx = 0.f, cmx = 0.f, dmn = 0.f, cmn = 0.f;
#pragma unroll
    for (int di = 0; di < 3; ++di) {
#pragma unroll
      for (int dj = 0; dj < 3; ++dj) {
        int gpy = th0 + ly + di - 1, gpx = tw0 + lx + dj - 1;  // padded-grid coords
        float dv = dpL[(ly + di) * 36 + lx + dj];
        float cv = cdpL[(ly + di) * 36 + lx + dj];
        bool inb = (gpy >= 0) & (gpy < H_ + 2) & (gpx >= 0) & (gpx < W_ + 2);
        float kx = inb ? dv * cv : -1.f;
        float kn = inb ? cv / (dv + EPS) : -1.f;
        if (kx > bkx) { bkx = kx; dmx = dv; cmx = cv; }  // first-wins (numpy argmax)
        if (kn > bkn) { bkn = kn; dmn = dv; cmn = cv; }
      }
    }
    dmxL[idx] = dmx; cmxL[idx] = cmx; dmnL[idx] = dmn; cmnL[idx] = cmn;
  }
  __syncthreads();

  const float wp = wprop[c];
  float wq[8];
#pragma unroll
  for (int t = 0; t < 8; ++t) wq[t] = wsd[c * 8 + t];  // [ord*4 + pair]

  const int offy[4] = {-1, -1, -1, 0};
  const int offx[4] = {-1, 0, 1, 1};

  for (int idx = tid; idx < 1024; idx += 256) {
    int ly = idx >> 5, lx = idx & 31;
    int hh = th0 + ly, ww = tw0 + lx;
#pragma unroll
    for (int p = 0; p < 4; ++p) {
      int n1 = (ly + offy[p] + 1) * 34 + (lx + offx[p] + 1);
      int n2 = (ly - offy[p] + 1) * 34 + (lx - offx[p] + 1);
      float r0 = dmnL[n1] / (dmxL[n2] + EPS);
      float r1 = dmxL[n1] / (dmnL[n2] + EPS);
      float cr0 = cmnL[n1] * cmxL[n2];
      float cr1 = cmxL[n1] * cmnL[n2];
      float x0 = fminf(fmaxf(r0, EPS), 1.0f);
      float x1 = fminf(fmaxf(r1, EPS), 1.0f);
      float dr0 = exp2f(wq[p] * log2f(x0));
      float dr1 = exp2f(wq[4 + p] * log2f(x1));
      // select ord with larger cr/dr; cross-multiplied (all >=0) -> no div/inf/NaN.
      // tie -> ord0 (numpy argmax first-wins).
      float ef, cf;
      if (cr1 * dr0 > cr0 * dr1) { ef = dr1; cf = cr1; } else { ef = dr0; cf = cr0; }
      int ei = (bc * 4 + p) * HW_ + hh * W_ + ww;
      float ev = e[ei], cev = ce[ei];
      float dn = wp * cev + cf;
      float e1 = (wp * cev * ev + cf * ef) / (dn + EPS);
      float ce1 = dn / (wp + 1.0f);
      XY[(b * CH4 + c * 4 + p) * HW_ + hh * W_ + ww] =
          (unsigned)f2bf(ce1 * e1) | ((unsigned)f2bf(ce1) << 16);
    }
  }
}

// ---- k2: per-pixel channel mix (two 128x128 GEMVs), scalar weights ----
__global__ void __launch_bounds__(256) k2_mix(const unsigned* __restrict__ XY,
                                              const float* __restrict__ cwT,
                                              const float* __restrict__ sums,
                                              unsigned* __restrict__ PQ) {
  int p = blockIdx.x * 256 + threadIdx.x;  // 147456 pixels exactly
  int b = p / HW_, hw = p - b * HW_;
  const unsigned* xp = XY + (b * CH4) * HW_ + hw;
  unsigned* qp = PQ + (b * CH4) * HW_ + hw;
  const float inv = 1.0f / (sums[0] + EPS);
#pragma unroll 1
  for (int ob = 0; ob < 4; ++ob) {
    float an[32], ad[32];
#pragma unroll
    for (int u = 0; u < 32; ++u) { an[u] = 0.f; ad[u] = 0.f; }
    for (int i = 0; i < CH4; ++i) {
      unsigned v = xp[i * HW_];
      float x = bflo(v), y = bfhi(v);
      const float* wr = cwT + i * 128 + ob * 32;  // uniform index -> s_load
#pragma unroll
      for (int u = 0; u < 32; ++u) { an[u] += x * wr[u]; ad[u] += y * wr[u]; }
    }
#pragma unroll
    for (int u = 0; u < 32; ++u) {
      qp[(ob * 32 + u) * HW_] =
          (unsigned)f2bf(an[u] * inv) | ((unsigned)f2bf(ad[u] * inv) << 16);
    }
  }
}

// ---- k3: depthwise 5x5 conv on P,Q + final ratios -> FP32 outputs ----
__global__ void __launch_bounds__(256) k3_conv(const unsigned* __restrict__ PQ,
                                               const float* __restrict__ sw,
                                               const float* __restrict__ sums,
                                               float* __restrict__ out0,
                                               float* __restrict__ out1) {
  int t = blockIdx.x;
  int tile = t % 36;
  int chb = t / 36;  // b*128+ch
  int ch = chb & 127;
  int th0 = (tile / 6) * 32, tw0 = (tile % 6) * 32;
  __shared__ float Pt[1296], Qt[1296];
  const unsigned* src = PQ + chb * HW_;
  int tid = threadIdx.x;
  for (int idx = tid; idx < 1296; idx += 256) {
    int ly = idx / 36, lx = idx % 36;
    int gy = th0 + ly - 2, gx = tw0 + lx - 2;
    unsigned v = 0;
    if (gy >= 0 && gy < H_ && gx >= 0 && gx < W_) v = src[gy * W_ + gx];
    Pt[idx] = bflo(v); Qt[idx] = bfhi(v);
  }
  __syncthreads();
  float wr[25];
#pragma unroll
  for (int k = 0; k < 25; ++k) wr[k] = sw[ch * 25 + k];
  float isw = 1.0f / (sums[1] + EPS);
  int x = tid & 31, yg = tid >> 5;  // 32 cols x 8 row-groups (4 rows each)
  float an[4] = {0, 0, 0, 0}, ad[4] = {0, 0, 0, 0};
#pragma unroll
  for (int rr = 0; rr < 8; ++rr) {
    int Lr = yg * 4 + rr;
    float pv[5], qv[5];
#pragma unroll
    for (int c5 = 0; c5 < 5; ++c5) {
      pv[c5] = Pt[Lr * 36 + x + c5];
      qv[c5] = Qt[Lr * 36 + x + c5];
    }
#pragma unroll
    for (int k = 0; k < 4; ++k) {
      int ky = rr - k;
      if (ky >= 0 && ky <= 4) {
#pragma unroll
        for (int c5 = 0; c5 < 5; ++c5) {
          an[k] += pv[c5] * wr[ky * 5 + c5];
          ad[k] += qv[c5] * wr[ky * 5 + c5];
        }
      }
    }
  }
#pragma unroll
  for (int k = 0; k < 4; ++k) {
    int hh = th0 + yg * 4 + k;
    int oi = chb * HW_ + hh * W_ + tw0 + x;
    out0[oi] = an[k] / (ad[k] + EPS);
    out1[oi] = ad[k] * isw;
  }
}

extern "C" void kernel_launch(void* const* d_in, const int* in_sizes, int n_in,
                              void* d_out, int out_size, void* d_ws, size_t ws_size,
                              hipStream_t stream) {
  // Inputs fp32 (reference: jnp.float32). Outputs fp32: d_out = float[37748736].
  const float* d = (const float*)d_in[0];
  const float* cd = (const float*)d_in[1];
  const float* e = (const float*)d_in[2];
  const float* ce = (const float*)d_in[3];
  const float* wprop = (const float*)d_in[4];
  const float* wsd = (const float*)d_in[5];
  const float* cw = (const float*)d_in[6];
  const float* sw = (const float*)d_in[7];

  // ws layout (75.6 MB): sums(64 f32) | cwT(16384 f32) | PQ(18874368 u32, bf16x2)
  // XY (bf16x2, 75.5 MB) is staged in the UPPER HALF of d_out (d_out is 151 MB
  // fp32). k2 fully consumes XY before k3 overwrites d_out with fp32 outputs.
  float* wsf = (float*)d_ws;
  float* sums = wsf;
  float* cwT = wsf + 64;
  unsigned* PQ = (unsigned*)(wsf + 64 + 16384);
  float* out0 = (float*)d_out;
  float* out1 = out0 + OUTELEMS;
  unsigned* XY = (unsigned*)(out0 + OUTELEMS);  // upper half of d_out

  hipLaunchKernelGGL(k0_prep, dim3(65), dim3(256), 0, stream, cw, sw, cwT, sums);
  hipLaunchKernelGGL(k1_stage1, dim3(36, 128), dim3(256), 0, stream, d, cd, e, ce,
                     wprop, wsd, XY);
  hipLaunchKernelGGL(k2_mix, dim3(576), dim3(256), 0, stream, XY, cwT, sums, PQ);
  hipLaunchKernelGGL(k3_conv, dim3(18432), dim3(256), 0, stream, PQ, sw, sums, out0,
                     out1);
}